// Round 11
// baseline (797.135 us; speedup 1.0000x reference)
//
#include <hip/hip_runtime.h>
#include <hip/hip_bf16.h>
#include <stdint.h>

#define KDIM 1024
#define NROW 4096
#define NCOL 4096
#define INFV 1e30f
#define INFBITS 0x7149F2CAu     // bits of 1e30f
#define BM 128
#define BK 32

#define SKROWS 4160             // skewed cost rows
#define DLAG   28               // extra epochs of slack per WG interface
#define EMAX   360              // 260 blocks + 15 wave-lag + 3*DLAG + margin

typedef __bf16 bf16x8 __attribute__((ext_vector_type(8)));
typedef float f32x4 __attribute__((ext_vector_type(4)));

#define CFENCE asm volatile("" ::: "memory")

__device__ __forceinline__ unsigned short f2bf(float f) {
    __hip_bfloat16 h = __float2bfloat16(f);
    return *reinterpret_cast<unsigned short*>(&h);
}

__device__ __forceinline__ void gll16(const void* gsrc, void* ldst) {
    __builtin_amdgcn_global_load_lds(
        (const __attribute__((address_space(1))) void*)gsrc,
        (__attribute__((address_space(3))) void*)ldst, 16, 0, 0);
}

// ---------------------------------------------------------------------------
// Kernel 1: row-normalize both trajectories, emit bf16
// ---------------------------------------------------------------------------
__global__ __launch_bounds__(256) void normalize_bf16(
    const float* __restrict__ t1, const float* __restrict__ t2,
    unsigned short* __restrict__ o1, unsigned short* __restrict__ o2)
{
    int b = blockIdx.x;
    int t = threadIdx.x;
    const float* src;
    unsigned short* dst;
    if (b < NROW) { src = t1 + (size_t)b * KDIM;          dst = o1 + (size_t)b * KDIM; }
    else          { src = t2 + (size_t)(b - NROW) * KDIM; dst = o2 + (size_t)(b - NROW) * KDIM; }

    float4 v = reinterpret_cast<const float4*>(src)[t];
    float ss = v.x * v.x + v.y * v.y + v.z * v.z + v.w * v.w;
    #pragma unroll
    for (int d = 32; d >= 1; d >>= 1) ss += __shfl_xor(ss, d, 64);

    __shared__ float wsum[4];
    int wave = t >> 6;
    if ((t & 63) == 0) wsum[wave] = ss;
    __syncthreads();
    float inv = 1.0f / (sqrtf(wsum[0] + wsum[1] + wsum[2] + wsum[3]) + 1e-8f);

    ushort4 o;
    o.x = f2bf(v.x * inv);
    o.y = f2bf(v.y * inv);
    o.z = f2bf(v.z * inv);
    o.w = f2bf(v.w * inv);
    reinterpret_cast<ushort4*>(dst)[t] = o;
}

// ---------------------------------------------------------------------------
// Kernel 2: skewed cost: skew[i + ((j>>2)&63)][j] = 1 - dot(t1n[i], t2n[j])
// ---------------------------------------------------------------------------
__global__ __launch_bounds__(256) void gemm_cost(
    const unsigned short* __restrict__ A,
    const unsigned short* __restrict__ B,
    unsigned short* __restrict__ Cs)    // skewed [SKROWS][4096]
{
    __shared__ __align__(16) unsigned short As[BM * BK];
    __shared__ __align__(16) unsigned short Bs[BM * BK];

    int t    = threadIdx.x;
    int lane = t & 63;
    int wave = t >> 6;
    int i0   = blockIdx.y * BM;
    int j0   = blockIdx.x * BM;

    f32x4 acc[4][4];
    f32x4 zero = {0.f, 0.f, 0.f, 0.f};
    #pragma unroll
    for (int m = 0; m < 4; ++m)
        #pragma unroll
        for (int n = 0; n < 4; ++n) acc[m][n] = zero;

    int frow = lane & 15;
    int fk   = (lane >> 4) * 8;
    int wr   = (wave >> 1) * 64;
    int wc   = (wave & 1) * 64;

    int srow = t >> 2;
    int scb  = (t & 3) * 8;

    uint4 ra0, ra1, rb0, rb1;
    {
        ra0 = *reinterpret_cast<const uint4*>(A + (size_t)(i0 + srow) * KDIM + scb);
        ra1 = *reinterpret_cast<const uint4*>(A + (size_t)(i0 + 64 + srow) * KDIM + scb);
        rb0 = *reinterpret_cast<const uint4*>(B + (size_t)(j0 + srow) * KDIM + scb);
        rb1 = *reinterpret_cast<const uint4*>(B + (size_t)(j0 + 64 + srow) * KDIM + scb);
    }

    for (int k0 = 0; k0 < KDIM; k0 += BK) {
        __syncthreads();
        *reinterpret_cast<uint4*>(As + (size_t)t * 8)         = ra0;
        *reinterpret_cast<uint4*>(As + (size_t)(256 + t) * 8) = ra1;
        *reinterpret_cast<uint4*>(Bs + (size_t)t * 8)         = rb0;
        *reinterpret_cast<uint4*>(Bs + (size_t)(256 + t) * 8) = rb1;
        __syncthreads();

        if (k0 + BK < KDIM) {
            int kn = k0 + BK;
            ra0 = *reinterpret_cast<const uint4*>(A + (size_t)(i0 + srow) * KDIM + kn + scb);
            ra1 = *reinterpret_cast<const uint4*>(A + (size_t)(i0 + 64 + srow) * KDIM + kn + scb);
            rb0 = *reinterpret_cast<const uint4*>(B + (size_t)(j0 + srow) * KDIM + kn + scb);
            rb1 = *reinterpret_cast<const uint4*>(B + (size_t)(j0 + 64 + srow) * KDIM + kn + scb);
        }

        bf16x8 af[4], bfr[4];
        #pragma unroll
        for (int m = 0; m < 4; ++m)
            af[m] = *reinterpret_cast<const bf16x8*>(As + (wr + m * 16 + frow) * BK + fk);
        #pragma unroll
        for (int n = 0; n < 4; ++n)
            bfr[n] = *reinterpret_cast<const bf16x8*>(Bs + (wc + n * 16 + frow) * BK + fk);

        #pragma unroll
        for (int m = 0; m < 4; ++m)
            #pragma unroll
            for (int n = 0; n < 4; ++n)
                acc[m][n] = __builtin_amdgcn_mfma_f32_16x16x32_bf16(af[m], bfr[n], acc[m][n], 0, 0, 0);
    }

    int crow = (lane >> 4) * 4;
    int ccol = lane & 15;
    #pragma unroll
    for (int n = 0; n < 4; ++n) {
        const int j  = j0 + wc + n * 16 + ccol;
        const int Lj = (j >> 2) & 63;
        #pragma unroll
        for (int m = 0; m < 4; ++m) {
            const int ibase = i0 + wr + m * 16 + crow;
            #pragma unroll
            for (int q = 0; q < 4; ++q)
                Cs[(size_t)(ibase + q + Lj) * NCOL + j] = f2bf(1.0f - acc[m][n][q]);
        }
    }
}

// ---------------------------------------------------------------------------
// Kernel 3: systolic DTW, 4 WGs x 4 waves (one wave per SIMD).
// Stripe s = 4*w + v owns cols [256s, +256); wave v of WG w processes block
// ib = e - 5v - DLAG*w at barrier epoch e. The DLAG=28 per-WG skew keeps
// each consumer ~6 epochs behind its producer's publishes, so the 3-ahead
// ring preloads always find valid tags (R9 ran at the publish edge ->
// coherent-point poll every epoch = 2.4us/epoch).
// Intra-WG handoff: LDS outRow ring + lgkmcnt(0)+s_barrier lockstep.
// Cost staging: 4-slot LDS ring, gll prefetch 3 ahead, exact VMEM counts
// -> s_waitcnt vmcnt(24/27/28).
// ---------------------------------------------------------------------------
__global__ __launch_bounds__(256, 1) void dtw_systolic(
    const unsigned short* __restrict__ cost,   // skewed [SKROWS][4096]
    unsigned long long* __restrict__ ring,     // [3][4096] + garb[4][64]
    float* __restrict__ out)
{
    __shared__ __align__(16) unsigned char clds[4 * 4 * 8192];  // [wave][slot][8KB]
    __shared__ float outRow[4][128];    // row-indexed boundary ring per stripe
    __shared__ float outRowD[4][128];   // dump for lanes != 63

    const int w    = blockIdx.x;
    const int tid  = threadIdx.x;
    const int v    = tid >> 6;
    const int lane = tid & 63;
    const int stripe = 4 * w + v;
    const bool gCon  = (v == 0 && w > 0);
    const bool gPro  = (v == 3 && w < 3);
    const bool first = (stripe == 0);
    const char* skewb = (const char*)cost;
    const unsigned long long* rseg = ring + (size_t)(w > 0 ? w - 1 : 0) * 4096;
    unsigned long long* wseg = ring + (size_t)w * 4096;
    unsigned long long* garb = ring + (size_t)3 * 4096 + w * 64;
    const unsigned lmin = (lane < 16) ? (unsigned)lane : 15u;
    const unsigned stripeByte = (unsigned)stripe * 512u + ((unsigned)(lane & 31) << 4);
    unsigned char* myclds = clds + v * 32768;
    float* opw = (lane == 63) ? outRow[v] : outRowD[v];

    float pd0 = INFV, pd1 = INFV, pd2 = INFV, pd3 = INFV;
    float lprev = (first && lane == 0) ? 0.0f : INFV;   // DP origin seed
    float d3p = INFV;
    unsigned ansb = INFBITS;
    unsigned long long rv0 = 0, rv1 = 0, rv2 = 0;

#define GLL8(STG) { int sg_ = (STG); sg_ = sg_ < 0 ? 0 : (sg_ > 259 ? 259 : sg_); \
    unsigned char* ldsb_ = myclds + (sg_ & 3) * 8192; \
    _Pragma("unroll") \
    for (int g_ = 0; g_ < 8; ++g_) { \
        int sr_ = 16 * sg_ + 2 * g_ + (lane >> 5); \
        if (sr_ > SKROWS - 1) sr_ = SKROWS - 1; \
        gll16(skewb + (size_t)sr_ * 8192 + stripeByte, ldsb_ + g_ * 1024); } }

#define RINGLD(DST, BI) { int pb_ = (BI); pb_ = pb_ < 0 ? 0 : (pb_ > 255 ? 255 : pb_); \
    DST = __hip_atomic_load(rseg + 16u * (unsigned)pb_ + lmin, \
                            __ATOMIC_RELAXED, __HIP_MEMORY_SCOPE_AGENT); }

#define DSTEP(K) { \
    const uint2 cu = *reinterpret_cast<const uint2*>(ldsaddr + (K) * 512); \
    const unsigned rbK = (unsigned)__builtin_amdgcn_readlane(rvhi, (K)); \
    const float lcur = __uint_as_float((unsigned)__builtin_amdgcn_update_dpp( \
        (int)rbK, (int)__float_as_uint(d3p), 0x138, 0xf, 0xf, false)); \
    const float c0 = __uint_as_float(cu.x << 16); \
    const float c1 = __uint_as_float(cu.x & 0xffff0000u); \
    const float c2 = __uint_as_float(cu.y << 16); \
    const float c3 = __uint_as_float(cu.y & 0xffff0000u); \
    const float n0 = c0 + fminf(pd0, lprev); \
    const float n1 = c1 + fminf(pd1, pd0); \
    const float n2 = c2 + fminf(pd2, pd1); \
    const float n3 = c3 + fminf(pd3, pd2); \
    const float e0 = fminf(lcur + c0, n0); \
    const float e1 = fminf(e0 + c1, n1); \
    const float e2 = fminf(e1 + c2, n2); \
    const float e3 = fminf(e2 + c3, n3); \
    opw[(unsigned)(rowbase + (K)) & 127u] = e3; \
    ansb = (tjb + (K) == 4158) ? __float_as_uint(e3) : ansb; \
    lprev = lcur; d3p = e3; \
    pd0 = e0; pd1 = e1; pd2 = e2; pd3 = e3; }

    // prologue: stage blocks 0..2 for wave 0 (WG0's wave 0 has no idle epochs;
    // other WGs' idle-epoch clamped prefetches re-stage these anyway)
    if (v == 0) {
        if (gCon) { GLL8(0) RINGLD(rv0, 0) GLL8(1) RINGLD(rv1, 1)
                    GLL8(2) RINGLD(rv2, 2) }
        else      { GLL8(0) GLL8(1) GLL8(2) }
    }

    #pragma unroll 1
    for (int e = 0; e < EMAX; ++e) {
        CFENCE;
        asm volatile("s_waitcnt lgkmcnt(0)" ::: "memory");  // LDS writes visible
        __builtin_amdgcn_s_barrier();
        CFENCE;

        const int ib = e - 5 * v - DLAG * w;   // this wave's block this epoch

        GLL8(ib + 3)                       // prefetch 3 ahead: slot != read slot
        unsigned long long rvN = 0;
        if (gCon) RINGLD(rvN, ib + 3)

        if (gCon)      { asm volatile("s_waitcnt vmcnt(28)" ::: "memory"); }
        else if (gPro) { asm volatile("s_waitcnt vmcnt(27)" ::: "memory"); }
        else           { asm volatile("s_waitcnt vmcnt(24)" ::: "memory"); }

        if (ib >= 0 && ib < 260) {
            // resolve boundary input (lanes 0..15 hold rows 16ib..16ib+15)
            int rvhi;
            if (gCon) {
                if (ib < 256) {
                    const unsigned expt = 16u * (unsigned)ib + lmin + 1u;
                    while (__ballot((unsigned)rv0 == expt) != ~0ull)
                        rv0 = __hip_atomic_load(rseg + 16u * (unsigned)ib + lmin,
                                                __ATOMIC_RELAXED, __HIP_MEMORY_SCOPE_AGENT);
                }
                rvhi = (int)(unsigned)(rv0 >> 32);
            } else if (v > 0) {
                rvhi = (int)__float_as_uint(
                    outRow[v - 1][(16u * (unsigned)ib + lmin) & 127u]);
            } else {
                rvhi = (int)INFBITS;        // stripe 0: left edge = +INF
            }

            const unsigned char* ldsaddr = myclds + (ib & 3) * 8192 + (lane << 3);
            const int rowbase = 16 * ib - 63;
            const int tjb = 16 * ib;

            DSTEP(0)  DSTEP(1)  DSTEP(2)  DSTEP(3)
            DSTEP(4)  DSTEP(5)  DSTEP(6)  DSTEP(7)
            DSTEP(8)  DSTEP(9)  DSTEP(10) DSTEP(11)
            DSTEP(12) DSTEP(13) DSTEP(14) DSTEP(15)
        }

        if (gPro) {     // publish this block's 16 boundary rows (or garb)
            const int r = 16 * ib - 63 + (int)lmin;
            const float bv = outRow[3][(unsigned)r & 127u];
            const bool valid = (lane < 16) && (ib >= 0) && (ib < 260) &&
                               (r >= 0) && (r <= 4095);
            if (lane < 16) {
                const unsigned long long pk =
                    ((unsigned long long)__float_as_uint(bv) << 32) | (unsigned)(r + 1);
                unsigned long long* sp = valid ? (wseg + r) : (garb + lane);
                (void)__hip_atomic_exchange(sp, pk, __ATOMIC_RELAXED,
                                            __HIP_MEMORY_SCOPE_AGENT);
            }
        }

        rv0 = rv1; rv1 = rv2; rv2 = rvN;
    }

#undef GLL8
#undef RINGLD
#undef DSTEP

    if (stripe == 15 && lane == 63) out[0] = 1.0f / (1.0f + __uint_as_float(ansb));
}

// ---------------------------------------------------------------------------
extern "C" void kernel_launch(void* const* d_in, const int* in_sizes, int n_in,
                              void* d_out, int out_size, void* d_ws, size_t ws_size,
                              hipStream_t stream)
{
    const float* t1 = (const float*)d_in[0];
    const float* t2 = (const float*)d_in[1];
    float* out = (float*)d_out;

    char* ws = (char*)d_ws;
    unsigned short* t1n  = (unsigned short*)ws;                                   // 8 MB
    unsigned short* t2n  = (unsigned short*)(ws + (size_t)NROW * KDIM * 2);       // 8 MB
    unsigned short* skew = (unsigned short*)(ws + (size_t)16 * 1024 * 1024);      // 34.1 MB
    unsigned long long* ring = (unsigned long long*)(ws + (size_t)52 * 1024 * 1024);
    // ring: 3 interface segments x 4096 slots + 4x64 garb slots (~130 KB)

    hipMemsetAsync(ring, 0, (size_t)(3 * 4096 + 4 * 64) * 8, stream);
    normalize_bf16<<<2 * NROW, 256, 0, stream>>>(t1, t2, t1n, t2n);
    gemm_cost<<<dim3(NCOL / BM, NROW / BM), 256, 0, stream>>>(t1n, t2n, skew);
    dtw_systolic<<<4, 256, 0, stream>>>(skew, ring, out);
}

// Round 12
// 730.696 us; speedup vs baseline: 1.0909x; 1.0909x over previous
//
#include <hip/hip_runtime.h>
#include <hip/hip_bf16.h>
#include <stdint.h>

#define KDIM 1024
#define NROW 4096
#define NCOL 4096
#define INFV 1e30f
#define INFBITS 0x7149F2CAu     // bits of 1e30f
#define BM 128
#define BK 32

#define SKROWS 4160             // skewed cost rows
#define DLAG   28               // extra epochs of slack per WG interface
#define EMAX   360              // 260 blocks + 15 wave-lag + 3*DLAG + margin

typedef __bf16 bf16x8 __attribute__((ext_vector_type(8)));
typedef float f32x4 __attribute__((ext_vector_type(4)));

#define CFENCE asm volatile("" ::: "memory")

__device__ __forceinline__ unsigned short f2bf(float f) {
    __hip_bfloat16 h = __float2bfloat16(f);
    return *reinterpret_cast<unsigned short*>(&h);
}

__device__ __forceinline__ void gll16(const void* gsrc, void* ldst) {
    __builtin_amdgcn_global_load_lds(
        (const __attribute__((address_space(1))) void*)gsrc,
        (__attribute__((address_space(3))) void*)ldst, 16, 0, 0);
}

// ---------------------------------------------------------------------------
// Kernel 1: row-normalize both trajectories, emit bf16
// ---------------------------------------------------------------------------
__global__ __launch_bounds__(256) void normalize_bf16(
    const float* __restrict__ t1, const float* __restrict__ t2,
    unsigned short* __restrict__ o1, unsigned short* __restrict__ o2)
{
    int b = blockIdx.x;
    int t = threadIdx.x;
    const float* src;
    unsigned short* dst;
    if (b < NROW) { src = t1 + (size_t)b * KDIM;          dst = o1 + (size_t)b * KDIM; }
    else          { src = t2 + (size_t)(b - NROW) * KDIM; dst = o2 + (size_t)(b - NROW) * KDIM; }

    float4 v = reinterpret_cast<const float4*>(src)[t];
    float ss = v.x * v.x + v.y * v.y + v.z * v.z + v.w * v.w;
    #pragma unroll
    for (int d = 32; d >= 1; d >>= 1) ss += __shfl_xor(ss, d, 64);

    __shared__ float wsum[4];
    int wave = t >> 6;
    if ((t & 63) == 0) wsum[wave] = ss;
    __syncthreads();
    float inv = 1.0f / (sqrtf(wsum[0] + wsum[1] + wsum[2] + wsum[3]) + 1e-8f);

    ushort4 o;
    o.x = f2bf(v.x * inv);
    o.y = f2bf(v.y * inv);
    o.z = f2bf(v.z * inv);
    o.w = f2bf(v.w * inv);
    reinterpret_cast<ushort4*>(dst)[t] = o;
}

// ---------------------------------------------------------------------------
// Kernel 2: skewed cost: skew[i + ((j>>2)&63)][j] = 1 - dot(t1n[i], t2n[j])
// ---------------------------------------------------------------------------
__global__ __launch_bounds__(256) void gemm_cost(
    const unsigned short* __restrict__ A,
    const unsigned short* __restrict__ B,
    unsigned short* __restrict__ Cs)    // skewed [SKROWS][4096]
{
    __shared__ __align__(16) unsigned short As[BM * BK];
    __shared__ __align__(16) unsigned short Bs[BM * BK];

    int t    = threadIdx.x;
    int lane = t & 63;
    int wave = t >> 6;
    int i0   = blockIdx.y * BM;
    int j0   = blockIdx.x * BM;

    f32x4 acc[4][4];
    f32x4 zero = {0.f, 0.f, 0.f, 0.f};
    #pragma unroll
    for (int m = 0; m < 4; ++m)
        #pragma unroll
        for (int n = 0; n < 4; ++n) acc[m][n] = zero;

    int frow = lane & 15;
    int fk   = (lane >> 4) * 8;
    int wr   = (wave >> 1) * 64;
    int wc   = (wave & 1) * 64;

    int srow = t >> 2;
    int scb  = (t & 3) * 8;

    uint4 ra0, ra1, rb0, rb1;
    {
        ra0 = *reinterpret_cast<const uint4*>(A + (size_t)(i0 + srow) * KDIM + scb);
        ra1 = *reinterpret_cast<const uint4*>(A + (size_t)(i0 + 64 + srow) * KDIM + scb);
        rb0 = *reinterpret_cast<const uint4*>(B + (size_t)(j0 + srow) * KDIM + scb);
        rb1 = *reinterpret_cast<const uint4*>(B + (size_t)(j0 + 64 + srow) * KDIM + scb);
    }

    for (int k0 = 0; k0 < KDIM; k0 += BK) {
        __syncthreads();
        *reinterpret_cast<uint4*>(As + (size_t)t * 8)         = ra0;
        *reinterpret_cast<uint4*>(As + (size_t)(256 + t) * 8) = ra1;
        *reinterpret_cast<uint4*>(Bs + (size_t)t * 8)         = rb0;
        *reinterpret_cast<uint4*>(Bs + (size_t)(256 + t) * 8) = rb1;
        __syncthreads();

        if (k0 + BK < KDIM) {
            int kn = k0 + BK;
            ra0 = *reinterpret_cast<const uint4*>(A + (size_t)(i0 + srow) * KDIM + kn + scb);
            ra1 = *reinterpret_cast<const uint4*>(A + (size_t)(i0 + 64 + srow) * KDIM + kn + scb);
            rb0 = *reinterpret_cast<const uint4*>(B + (size_t)(j0 + srow) * KDIM + kn + scb);
            rb1 = *reinterpret_cast<const uint4*>(B + (size_t)(j0 + 64 + srow) * KDIM + kn + scb);
        }

        bf16x8 af[4], bfr[4];
        #pragma unroll
        for (int m = 0; m < 4; ++m)
            af[m] = *reinterpret_cast<const bf16x8*>(As + (wr + m * 16 + frow) * BK + fk);
        #pragma unroll
        for (int n = 0; n < 4; ++n)
            bfr[n] = *reinterpret_cast<const bf16x8*>(Bs + (wc + n * 16 + frow) * BK + fk);

        #pragma unroll
        for (int m = 0; m < 4; ++m)
            #pragma unroll
            for (int n = 0; n < 4; ++n)
                acc[m][n] = __builtin_amdgcn_mfma_f32_16x16x32_bf16(af[m], bfr[n], acc[m][n], 0, 0, 0);
    }

    int crow = (lane >> 4) * 4;
    int ccol = lane & 15;
    #pragma unroll
    for (int n = 0; n < 4; ++n) {
        const int j  = j0 + wc + n * 16 + ccol;
        const int Lj = (j >> 2) & 63;
        #pragma unroll
        for (int m = 0; m < 4; ++m) {
            const int ibase = i0 + wr + m * 16 + crow;
            #pragma unroll
            for (int q = 0; q < 4; ++q)
                Cs[(size_t)(ibase + q + Lj) * NCOL + j] = f2bf(1.0f - acc[m][n][q]);
        }
    }
}

// ---------------------------------------------------------------------------
// Kernel 3: systolic DTW, 4 WGs x 4 waves (one wave per SIMD).
// Stripe s = 4*w + v owns cols [256s, +256); wave v of WG w processes block
// ib = e - 5v - DLAG*w at barrier epoch e (DLAG slack -> no steady-state
// polls on the 3 global interfaces). Epoch body: batch all 16 cost ds_reads
// into NAMED registers up front (one latency exposure, not 16 serialized),
// then 16 pure-VALU steps (DPP chain). This attacks R10's 2us/epoch floor
// (per-step LDS read latency was serialized by the inter-step LDS store).
// ---------------------------------------------------------------------------
__global__ __launch_bounds__(256, 1) void dtw_systolic(
    const unsigned short* __restrict__ cost,   // skewed [SKROWS][4096]
    unsigned long long* __restrict__ ring,     // [3][4096] + garb[4][64]
    float* __restrict__ out)
{
    __shared__ __align__(16) unsigned char clds[4 * 4 * 8192];  // [wave][slot][8KB]
    __shared__ float outRow[4][128];    // row-indexed boundary ring per stripe
    __shared__ float outRowD[4][128];   // dump for lanes != 63

    const int w    = blockIdx.x;
    const int tid  = threadIdx.x;
    const int v    = tid >> 6;
    const int lane = tid & 63;
    const int stripe = 4 * w + v;
    const bool gCon  = (v == 0 && w > 0);
    const bool gPro  = (v == 3 && w < 3);
    const bool first = (stripe == 0);
    const char* skewb = (const char*)cost;
    const unsigned long long* rseg = ring + (size_t)(w > 0 ? w - 1 : 0) * 4096;
    unsigned long long* wseg = ring + (size_t)w * 4096;
    unsigned long long* garb = ring + (size_t)3 * 4096 + w * 64;
    const unsigned lmin = (lane < 16) ? (unsigned)lane : 15u;
    const unsigned stripeByte = (unsigned)stripe * 512u + ((unsigned)(lane & 31) << 4);
    unsigned char* myclds = clds + v * 32768;
    float* opw = (lane == 63) ? outRow[v] : outRowD[v];

    float pd0 = INFV, pd1 = INFV, pd2 = INFV, pd3 = INFV;
    float lprev = (first && lane == 0) ? 0.0f : INFV;   // DP origin seed
    float d3p = INFV;
    unsigned ansb = INFBITS;
    unsigned long long rv0 = 0, rv1 = 0, rv2 = 0;

#define GLL8(STG) { int sg_ = (STG); sg_ = sg_ < 0 ? 0 : (sg_ > 259 ? 259 : sg_); \
    unsigned char* ldsb_ = myclds + (sg_ & 3) * 8192; \
    _Pragma("unroll") \
    for (int g_ = 0; g_ < 8; ++g_) { \
        int sr_ = 16 * sg_ + 2 * g_ + (lane >> 5); \
        if (sr_ > SKROWS - 1) sr_ = SKROWS - 1; \
        gll16(skewb + (size_t)sr_ * 8192 + stripeByte, ldsb_ + g_ * 1024); } }

#define RINGLD(DST, BI) { int pb_ = (BI); pb_ = pb_ < 0 ? 0 : (pb_ > 255 ? 255 : pb_); \
    DST = __hip_atomic_load(rseg + 16u * (unsigned)pb_ + lmin, \
                            __ATOMIC_RELAXED, __HIP_MEMORY_SCOPE_AGENT); }

// pure-VALU step: cost uint2 already in a named register
#define DCOMP(K, CU) { \
    const unsigned rbK = (unsigned)__builtin_amdgcn_readlane(rvhi, (K)); \
    const float lcur = __uint_as_float((unsigned)__builtin_amdgcn_update_dpp( \
        (int)rbK, (int)__float_as_uint(d3p), 0x138, 0xf, 0xf, false)); \
    const float c0 = __uint_as_float(CU.x << 16); \
    const float c1 = __uint_as_float(CU.x & 0xffff0000u); \
    const float c2 = __uint_as_float(CU.y << 16); \
    const float c3 = __uint_as_float(CU.y & 0xffff0000u); \
    const float n0 = c0 + fminf(pd0, lprev); \
    const float n1 = c1 + fminf(pd1, pd0); \
    const float n2 = c2 + fminf(pd2, pd1); \
    const float n3 = c3 + fminf(pd3, pd2); \
    const float e0 = fminf(lcur + c0, n0); \
    const float e1 = fminf(e0 + c1, n1); \
    const float e2 = fminf(e1 + c2, n2); \
    const float e3 = fminf(e2 + c3, n3); \
    opw[(unsigned)(rowbase + (K)) & 127u] = e3; \
    ansb = (tjb + (K) == 4158) ? __float_as_uint(e3) : ansb; \
    lprev = lcur; d3p = e3; \
    pd0 = e0; pd1 = e1; pd2 = e2; pd3 = e3; }

    // prologue: stage blocks 0..2 for wave 0
    if (v == 0) {
        if (gCon) { GLL8(0) RINGLD(rv0, 0) GLL8(1) RINGLD(rv1, 1)
                    GLL8(2) RINGLD(rv2, 2) }
        else      { GLL8(0) GLL8(1) GLL8(2) }
    }

    #pragma unroll 1
    for (int e = 0; e < EMAX; ++e) {
        CFENCE;
        asm volatile("s_waitcnt lgkmcnt(0)" ::: "memory");  // LDS writes visible
        __builtin_amdgcn_s_barrier();
        CFENCE;

        const int ib = e - 5 * v - DLAG * w;   // this wave's block this epoch

        GLL8(ib + 3)                       // prefetch 3 ahead: slot != read slot
        unsigned long long rvN = 0;
        if (gCon) RINGLD(rvN, ib + 3)

        if (gCon)      { asm volatile("s_waitcnt vmcnt(28)" ::: "memory"); }
        else if (gPro) { asm volatile("s_waitcnt vmcnt(27)" ::: "memory"); }
        else           { asm volatile("s_waitcnt vmcnt(24)" ::: "memory"); }

        if (ib >= 0 && ib < 260) {
            // batch-load the 16 cost uint2s into named regs (one latency hit)
            const uint2* lu = reinterpret_cast<const uint2*>(
                myclds + (ib & 3) * 8192 + (lane << 3));
            const uint2 cc0  = lu[0 * 64],  cc1  = lu[1 * 64];
            const uint2 cc2  = lu[2 * 64],  cc3  = lu[3 * 64];
            const uint2 cc4  = lu[4 * 64],  cc5  = lu[5 * 64];
            const uint2 cc6  = lu[6 * 64],  cc7  = lu[7 * 64];
            const uint2 cc8  = lu[8 * 64],  cc9  = lu[9 * 64];
            const uint2 cc10 = lu[10 * 64], cc11 = lu[11 * 64];
            const uint2 cc12 = lu[12 * 64], cc13 = lu[13 * 64];
            const uint2 cc14 = lu[14 * 64], cc15 = lu[15 * 64];

            // resolve boundary input (lanes 0..15 hold rows 16ib..16ib+15)
            int rvhi;
            if (gCon) {
                if (ib < 256) {
                    const unsigned expt = 16u * (unsigned)ib + lmin + 1u;
                    while (__ballot((unsigned)rv0 == expt) != ~0ull)
                        rv0 = __hip_atomic_load(rseg + 16u * (unsigned)ib + lmin,
                                                __ATOMIC_RELAXED, __HIP_MEMORY_SCOPE_AGENT);
                }
                rvhi = (int)(unsigned)(rv0 >> 32);
            } else if (v > 0) {
                rvhi = (int)__float_as_uint(
                    outRow[v - 1][(16u * (unsigned)ib + lmin) & 127u]);
            } else {
                rvhi = (int)INFBITS;        // stripe 0: left edge = +INF
            }

            const int rowbase = 16 * ib - 63;
            const int tjb = 16 * ib;

            DCOMP(0,  cc0)  DCOMP(1,  cc1)  DCOMP(2,  cc2)  DCOMP(3,  cc3)
            DCOMP(4,  cc4)  DCOMP(5,  cc5)  DCOMP(6,  cc6)  DCOMP(7,  cc7)
            DCOMP(8,  cc8)  DCOMP(9,  cc9)  DCOMP(10, cc10) DCOMP(11, cc11)
            DCOMP(12, cc12) DCOMP(13, cc13) DCOMP(14, cc14) DCOMP(15, cc15)
        }

        if (gPro) {     // publish this block's 16 boundary rows (or garb)
            const int r = 16 * ib - 63 + (int)lmin;
            const float bv = outRow[3][(unsigned)r & 127u];
            const bool valid = (lane < 16) && (ib >= 0) && (ib < 260) &&
                               (r >= 0) && (r <= 4095);
            if (lane < 16) {
                const unsigned long long pk =
                    ((unsigned long long)__float_as_uint(bv) << 32) | (unsigned)(r + 1);
                unsigned long long* sp = valid ? (wseg + r) : (garb + lane);
                (void)__hip_atomic_exchange(sp, pk, __ATOMIC_RELAXED,
                                            __HIP_MEMORY_SCOPE_AGENT);
            }
        }

        rv0 = rv1; rv1 = rv2; rv2 = rvN;
    }

#undef GLL8
#undef RINGLD
#undef DCOMP

    if (stripe == 15 && lane == 63) out[0] = 1.0f / (1.0f + __uint_as_float(ansb));
}

// ---------------------------------------------------------------------------
extern "C" void kernel_launch(void* const* d_in, const int* in_sizes, int n_in,
                              void* d_out, int out_size, void* d_ws, size_t ws_size,
                              hipStream_t stream)
{
    const float* t1 = (const float*)d_in[0];
    const float* t2 = (const float*)d_in[1];
    float* out = (float*)d_out;

    char* ws = (char*)d_ws;
    unsigned short* t1n  = (unsigned short*)ws;                                   // 8 MB
    unsigned short* t2n  = (unsigned short*)(ws + (size_t)NROW * KDIM * 2);       // 8 MB
    unsigned short* skew = (unsigned short*)(ws + (size_t)16 * 1024 * 1024);      // 34.1 MB
    unsigned long long* ring = (unsigned long long*)(ws + (size_t)52 * 1024 * 1024);
    // ring: 3 interface segments x 4096 slots + 4x64 garb slots (~130 KB)

    hipMemsetAsync(ring, 0, (size_t)(3 * 4096 + 4 * 64) * 8, stream);
    normalize_bf16<<<2 * NROW, 256, 0, stream>>>(t1, t2, t1n, t2n);
    gemm_cost<<<dim3(NCOL / BM, NROW / BM), 256, 0, stream>>>(t1n, t2n, skew);
    dtw_systolic<<<4, 256, 0, stream>>>(skew, ring, out);
}

// Round 13
// 644.679 us; speedup vs baseline: 1.2365x; 1.1334x over previous
//
#include <hip/hip_runtime.h>
#include <hip/hip_bf16.h>
#include <stdint.h>

#define KDIM 1024
#define NROW 4096
#define NCOL 4096
#define INFV 1e30f
#define INFBITS 0x7149F2CAu     // bits of 1e30f
#define BM 128
#define BK 32

#define SKROWS 4160             // skewed cost rows
#define DLAG   28               // extra epochs of slack per WG interface (min 22)
#define EMAX   360              // 260 blocks + 15 wave-lag + 3*DLAG + margin

typedef __bf16 bf16x8 __attribute__((ext_vector_type(8)));
typedef float f32x4 __attribute__((ext_vector_type(4)));

#define CFENCE asm volatile("" ::: "memory")

__device__ __forceinline__ unsigned short f2bf(float f) {
    __hip_bfloat16 h = __float2bfloat16(f);
    return *reinterpret_cast<unsigned short*>(&h);
}

__device__ __forceinline__ void gll16(const void* gsrc, void* ldst) {
    __builtin_amdgcn_global_load_lds(
        (const __attribute__((address_space(1))) void*)gsrc,
        (__attribute__((address_space(3))) void*)ldst, 16, 0, 0);
}

// ---------------------------------------------------------------------------
// Kernel 1: row-normalize both trajectories, emit bf16
// ---------------------------------------------------------------------------
__global__ __launch_bounds__(256) void normalize_bf16(
    const float* __restrict__ t1, const float* __restrict__ t2,
    unsigned short* __restrict__ o1, unsigned short* __restrict__ o2)
{
    int b = blockIdx.x;
    int t = threadIdx.x;
    const float* src;
    unsigned short* dst;
    if (b < NROW) { src = t1 + (size_t)b * KDIM;          dst = o1 + (size_t)b * KDIM; }
    else          { src = t2 + (size_t)(b - NROW) * KDIM; dst = o2 + (size_t)(b - NROW) * KDIM; }

    float4 v = reinterpret_cast<const float4*>(src)[t];
    float ss = v.x * v.x + v.y * v.y + v.z * v.z + v.w * v.w;
    #pragma unroll
    for (int d = 32; d >= 1; d >>= 1) ss += __shfl_xor(ss, d, 64);

    __shared__ float wsum[4];
    int wave = t >> 6;
    if ((t & 63) == 0) wsum[wave] = ss;
    __syncthreads();
    float inv = 1.0f / (sqrtf(wsum[0] + wsum[1] + wsum[2] + wsum[3]) + 1e-8f);

    ushort4 o;
    o.x = f2bf(v.x * inv);
    o.y = f2bf(v.y * inv);
    o.z = f2bf(v.z * inv);
    o.w = f2bf(v.w * inv);
    reinterpret_cast<ushort4*>(dst)[t] = o;
}

// ---------------------------------------------------------------------------
// Kernel 2: skewed cost: skew[i + ((j>>2)&63)][j] = 1 - dot(t1n[i], t2n[j])
// ---------------------------------------------------------------------------
__global__ __launch_bounds__(256) void gemm_cost(
    const unsigned short* __restrict__ A,
    const unsigned short* __restrict__ B,
    unsigned short* __restrict__ Cs)    // skewed [SKROWS][4096]
{
    __shared__ __align__(16) unsigned short As[BM * BK];
    __shared__ __align__(16) unsigned short Bs[BM * BK];

    int t    = threadIdx.x;
    int lane = t & 63;
    int wave = t >> 6;
    int i0   = blockIdx.y * BM;
    int j0   = blockIdx.x * BM;

    f32x4 acc[4][4];
    f32x4 zero = {0.f, 0.f, 0.f, 0.f};
    #pragma unroll
    for (int m = 0; m < 4; ++m)
        #pragma unroll
        for (int n = 0; n < 4; ++n) acc[m][n] = zero;

    int frow = lane & 15;
    int fk   = (lane >> 4) * 8;
    int wr   = (wave >> 1) * 64;
    int wc   = (wave & 1) * 64;

    int srow = t >> 2;
    int scb  = (t & 3) * 8;

    uint4 ra0, ra1, rb0, rb1;
    {
        ra0 = *reinterpret_cast<const uint4*>(A + (size_t)(i0 + srow) * KDIM + scb);
        ra1 = *reinterpret_cast<const uint4*>(A + (size_t)(i0 + 64 + srow) * KDIM + scb);
        rb0 = *reinterpret_cast<const uint4*>(B + (size_t)(j0 + srow) * KDIM + scb);
        rb1 = *reinterpret_cast<const uint4*>(B + (size_t)(j0 + 64 + srow) * KDIM + scb);
    }

    for (int k0 = 0; k0 < KDIM; k0 += BK) {
        __syncthreads();
        *reinterpret_cast<uint4*>(As + (size_t)t * 8)         = ra0;
        *reinterpret_cast<uint4*>(As + (size_t)(256 + t) * 8) = ra1;
        *reinterpret_cast<uint4*>(Bs + (size_t)t * 8)         = rb0;
        *reinterpret_cast<uint4*>(Bs + (size_t)(256 + t) * 8) = rb1;
        __syncthreads();

        if (k0 + BK < KDIM) {
            int kn = k0 + BK;
            ra0 = *reinterpret_cast<const uint4*>(A + (size_t)(i0 + srow) * KDIM + kn + scb);
            ra1 = *reinterpret_cast<const uint4*>(A + (size_t)(i0 + 64 + srow) * KDIM + kn + scb);
            rb0 = *reinterpret_cast<const uint4*>(B + (size_t)(j0 + srow) * KDIM + kn + scb);
            rb1 = *reinterpret_cast<const uint4*>(B + (size_t)(j0 + 64 + srow) * KDIM + kn + scb);
        }

        bf16x8 af[4], bfr[4];
        #pragma unroll
        for (int m = 0; m < 4; ++m)
            af[m] = *reinterpret_cast<const bf16x8*>(As + (wr + m * 16 + frow) * BK + fk);
        #pragma unroll
        for (int n = 0; n < 4; ++n)
            bfr[n] = *reinterpret_cast<const bf16x8*>(Bs + (wc + n * 16 + frow) * BK + fk);

        #pragma unroll
        for (int m = 0; m < 4; ++m)
            #pragma unroll
            for (int n = 0; n < 4; ++n)
                acc[m][n] = __builtin_amdgcn_mfma_f32_16x16x32_bf16(af[m], bfr[n], acc[m][n], 0, 0, 0);
    }

    int crow = (lane >> 4) * 4;
    int ccol = lane & 15;
    #pragma unroll
    for (int n = 0; n < 4; ++n) {
        const int j  = j0 + wc + n * 16 + ccol;
        const int Lj = (j >> 2) & 63;
        #pragma unroll
        for (int m = 0; m < 4; ++m) {
            const int ibase = i0 + wr + m * 16 + crow;
            #pragma unroll
            for (int q = 0; q < 4; ++q)
                Cs[(size_t)(ibase + q + Lj) * NCOL + j] = f2bf(1.0f - acc[m][n][q]);
        }
    }
}

// ---------------------------------------------------------------------------
// Kernel 3: systolic DTW, 4 WGs x 4 waves (one wave per SIMD).
// ib = e - 5v - DLAG*w. Key change vs R11: the ring preload is inline-asm
// global_load_dwordx2 sc0 sc1 -> the compiler's waitcnt pass no longer sees
// a load feeding the ballot, so it cannot insert its own vmcnt(0) drain of
// the GLL8 DMA queue every epoch (R11's ~2us/epoch floor). Consumption
// safety is my counted vmcnt(27) whose asm BINDS rv0 ("+v") so the ballot
// cannot be hoisted above the wait (rule #18). sc0 sc1 bypasses the
// non-coherent L2 (stale-zero hazard for cross-XCD preloads).
// ---------------------------------------------------------------------------
__global__ __launch_bounds__(256, 1) void dtw_systolic(
    const unsigned short* __restrict__ cost,   // skewed [SKROWS][4096]
    unsigned long long* __restrict__ ring,     // [3][4096] + garb[4][64]
    float* __restrict__ out)
{
    __shared__ __align__(16) unsigned char clds[4 * 4 * 8192];  // [wave][slot][8KB]
    __shared__ float outRow[4][128];    // row-indexed boundary ring per stripe
    __shared__ float outRowD[4][128];   // dump for lanes != 63

    const int w    = blockIdx.x;
    const int tid  = threadIdx.x;
    const int v    = tid >> 6;
    const int lane = tid & 63;
    const int stripe = 4 * w + v;
    const bool gCon  = (v == 0 && w > 0);
    const bool gPro  = (v == 3 && w < 3);
    const bool first = (stripe == 0);
    const char* skewb = (const char*)cost;
    const unsigned long long* rseg = ring + (size_t)(w > 0 ? w - 1 : 0) * 4096;
    unsigned long long* wseg = ring + (size_t)w * 4096;
    unsigned long long* garb = ring + (size_t)3 * 4096 + w * 64;
    const unsigned lmin = (lane < 16) ? (unsigned)lane : 15u;
    const unsigned stripeByte = (unsigned)stripe * 512u + ((unsigned)(lane & 31) << 4);
    unsigned char* myclds = clds + v * 32768;
    float* opw = (lane == 63) ? outRow[v] : outRowD[v];

    float pd0 = INFV, pd1 = INFV, pd2 = INFV, pd3 = INFV;
    float lprev = (first && lane == 0) ? 0.0f : INFV;   // DP origin seed
    float d3p = INFV;
    unsigned ansb = INFBITS;
    unsigned long long rv0 = 0, rv1 = 0, rv2 = 0;

#define GLL8(STG) { int sg_ = (STG); sg_ = sg_ < 0 ? 0 : (sg_ > 259 ? 259 : sg_); \
    unsigned char* ldsb_ = myclds + (sg_ & 3) * 8192; \
    _Pragma("unroll") \
    for (int g_ = 0; g_ < 8; ++g_) { \
        int sr_ = 16 * sg_ + 2 * g_ + (lane >> 5); \
        if (sr_ > SKROWS - 1) sr_ = SKROWS - 1; \
        gll16(skewb + (size_t)sr_ * 8192 + stripeByte, ldsb_ + g_ * 1024); } }

// ring preload via asm: invisible to compiler's waitcnt pass; sc0 sc1 =
// coherent-point read (producer publishes via atomic_exchange RMW)
#define RINGLD(DST, BI) { int pb_ = (BI); pb_ = pb_ < 0 ? 0 : (pb_ > 255 ? 255 : pb_); \
    const unsigned off_ = (16u * (unsigned)pb_ + lmin) * 8u; \
    asm volatile("global_load_dwordx2 %0, %1, %2 sc0 sc1" \
                 : "=v"(DST) : "v"(off_), "s"(rseg) : "memory"); }

// pure-VALU step: cost uint2 already in a named register
#define DCOMP(K, CU) { \
    const unsigned rbK = (unsigned)__builtin_amdgcn_readlane(rvhi, (K)); \
    const float lcur = __uint_as_float((unsigned)__builtin_amdgcn_update_dpp( \
        (int)rbK, (int)__float_as_uint(d3p), 0x138, 0xf, 0xf, false)); \
    const float c0 = __uint_as_float(CU.x << 16); \
    const float c1 = __uint_as_float(CU.x & 0xffff0000u); \
    const float c2 = __uint_as_float(CU.y << 16); \
    const float c3 = __uint_as_float(CU.y & 0xffff0000u); \
    const float n0 = c0 + fminf(pd0, lprev); \
    const float n1 = c1 + fminf(pd1, pd0); \
    const float n2 = c2 + fminf(pd2, pd1); \
    const float n3 = c3 + fminf(pd3, pd2); \
    const float e0 = fminf(lcur + c0, n0); \
    const float e1 = fminf(e0 + c1, n1); \
    const float e2 = fminf(e1 + c2, n2); \
    const float e3 = fminf(e2 + c3, n3); \
    opw[(unsigned)(rowbase + (K)) & 127u] = e3; \
    ansb = (tjb + (K) == 4158) ? __float_as_uint(e3) : ansb; \
    lprev = lcur; d3p = e3; \
    pd0 = e0; pd1 = e1; pd2 = e2; pd3 = e3; }

    // prologue: stage blocks 0..2 for wave 0
    if (v == 0) {
        if (gCon) { GLL8(0) RINGLD(rv0, 0) GLL8(1) RINGLD(rv1, 1)
                    GLL8(2) RINGLD(rv2, 2) }
        else      { GLL8(0) GLL8(1) GLL8(2) }
    }

    #pragma unroll 1
    for (int e = 0; e < EMAX; ++e) {
        CFENCE;
        asm volatile("s_waitcnt lgkmcnt(0)" ::: "memory");  // LDS writes visible
        __builtin_amdgcn_s_barrier();
        CFENCE;

        const int ib = e - 5 * v - DLAG * w;   // this wave's block this epoch

        GLL8(ib + 3)                       // prefetch 3 ahead: slot != read slot
        unsigned long long rvN = 0;
        if (gCon) RINGLD(rvN, ib + 3)

        if (gCon) {
            // 9 ops/epoch (8 gll + 1 asm ringld), 3 epochs in flight + this
            // epoch's 9 = 36; wait for the oldest 9 (incl. rv0's load).
            // Binding rv0 gives the ballot a hard dep on the post-wait value.
            asm volatile("s_waitcnt vmcnt(27)" : "+v"(rv0) :: "memory");
        } else if (gPro) {
            asm volatile("s_waitcnt vmcnt(27)" ::: "memory");
        } else {
            asm volatile("s_waitcnt vmcnt(24)" ::: "memory");
        }

        if (ib >= 0 && ib < 260) {
            // batch-load the 16 cost uint2s into named regs (one latency hit)
            const uint2* lu = reinterpret_cast<const uint2*>(
                myclds + (ib & 3) * 8192 + (lane << 3));
            const uint2 cc0  = lu[0 * 64],  cc1  = lu[1 * 64];
            const uint2 cc2  = lu[2 * 64],  cc3  = lu[3 * 64];
            const uint2 cc4  = lu[4 * 64],  cc5  = lu[5 * 64];
            const uint2 cc6  = lu[6 * 64],  cc7  = lu[7 * 64];
            const uint2 cc8  = lu[8 * 64],  cc9  = lu[9 * 64];
            const uint2 cc10 = lu[10 * 64], cc11 = lu[11 * 64];
            const uint2 cc12 = lu[12 * 64], cc13 = lu[13 * 64];
            const uint2 cc14 = lu[14 * 64], cc15 = lu[15 * 64];

            // resolve boundary input (lanes 0..15 hold rows 16ib..16ib+15)
            int rvhi;
            if (gCon) {
                if (ib < 256) {
                    const unsigned expt = 16u * (unsigned)ib + lmin + 1u;
                    while (__ballot((unsigned)rv0 == expt) != ~0ull)
                        rv0 = __hip_atomic_load(rseg + 16u * (unsigned)ib + lmin,
                                                __ATOMIC_RELAXED, __HIP_MEMORY_SCOPE_AGENT);
                }
                rvhi = (int)(unsigned)(rv0 >> 32);
            } else if (v > 0) {
                rvhi = (int)__float_as_uint(
                    outRow[v - 1][(16u * (unsigned)ib + lmin) & 127u]);
            } else {
                rvhi = (int)INFBITS;        // stripe 0: left edge = +INF
            }

            const int rowbase = 16 * ib - 63;
            const int tjb = 16 * ib;

            DCOMP(0,  cc0)  DCOMP(1,  cc1)  DCOMP(2,  cc2)  DCOMP(3,  cc3)
            DCOMP(4,  cc4)  DCOMP(5,  cc5)  DCOMP(6,  cc6)  DCOMP(7,  cc7)
            DCOMP(8,  cc8)  DCOMP(9,  cc9)  DCOMP(10, cc10) DCOMP(11, cc11)
            DCOMP(12, cc12) DCOMP(13, cc13) DCOMP(14, cc14) DCOMP(15, cc15)
        }

        if (gPro) {     // publish this block's 16 boundary rows (or garb)
            const int r = 16 * ib - 63 + (int)lmin;
            const float bv = outRow[3][(unsigned)r & 127u];
            const bool valid = (lane < 16) && (ib >= 0) && (ib < 260) &&
                               (r >= 0) && (r <= 4095);
            if (lane < 16) {
                const unsigned long long pk =
                    ((unsigned long long)__float_as_uint(bv) << 32) | (unsigned)(r + 1);
                unsigned long long* sp = valid ? (wseg + r) : (garb + lane);
                (void)__hip_atomic_exchange(sp, pk, __ATOMIC_RELAXED,
                                            __HIP_MEMORY_SCOPE_AGENT);
            }
        }

        rv0 = rv1; rv1 = rv2; rv2 = rvN;
    }

#undef GLL8
#undef RINGLD
#undef DCOMP

    if (stripe == 15 && lane == 63) out[0] = 1.0f / (1.0f + __uint_as_float(ansb));
}

// ---------------------------------------------------------------------------
extern "C" void kernel_launch(void* const* d_in, const int* in_sizes, int n_in,
                              void* d_out, int out_size, void* d_ws, size_t ws_size,
                              hipStream_t stream)
{
    const float* t1 = (const float*)d_in[0];
    const float* t2 = (const float*)d_in[1];
    float* out = (float*)d_out;

    char* ws = (char*)d_ws;
    unsigned short* t1n  = (unsigned short*)ws;                                   // 8 MB
    unsigned short* t2n  = (unsigned short*)(ws + (size_t)NROW * KDIM * 2);       // 8 MB
    unsigned short* skew = (unsigned short*)(ws + (size_t)16 * 1024 * 1024);      // 34.1 MB
    unsigned long long* ring = (unsigned long long*)(ws + (size_t)52 * 1024 * 1024);
    // ring: 3 interface segments x 4096 slots + 4x64 garb slots (~130 KB)

    hipMemsetAsync(ring, 0, (size_t)(3 * 4096 + 4 * 64) * 8, stream);
    normalize_bf16<<<2 * NROW, 256, 0, stream>>>(t1, t2, t1n, t2n);
    gemm_cost<<<dim3(NCOL / BM, NROW / BM), 256, 0, stream>>>(t1n, t2n, skew);
    dtw_systolic<<<4, 256, 0, stream>>>(skew, ring, out);
}

// Round 14
// 600.770 us; speedup vs baseline: 1.3269x; 1.0731x over previous
//
#include <hip/hip_runtime.h>
#include <hip/hip_bf16.h>
#include <stdint.h>

#define KDIM 1024
#define NROW 4096
#define NCOL 4096
#define INFV 1e30f
#define INFBITS 0x7149F2CAu     // bits of 1e30f
#define BM 128
#define BK 32

#define SKROWS 4160             // skewed cost rows
#define NBLK32 130              // 32-step blocks (tj 0..4159)
#define DLAG   16               // per-WG-interface epoch skew (slack = DLAG-10)
#define EMAX   190              // last block: 129 + 3*3 + 3*DLAG = 186

typedef __bf16 bf16x8 __attribute__((ext_vector_type(8)));
typedef float f32x4 __attribute__((ext_vector_type(4)));

#define CFENCE asm volatile("" ::: "memory")

__device__ __forceinline__ unsigned short f2bf(float f) {
    __hip_bfloat16 h = __float2bfloat16(f);
    return *reinterpret_cast<unsigned short*>(&h);
}

__device__ __forceinline__ void gll16(const void* gsrc, void* ldst) {
    __builtin_amdgcn_global_load_lds(
        (const __attribute__((address_space(1))) void*)gsrc,
        (__attribute__((address_space(3))) void*)ldst, 16, 0, 0);
}

// ---------------------------------------------------------------------------
// Kernel 1: row-normalize both trajectories, emit bf16
// ---------------------------------------------------------------------------
__global__ __launch_bounds__(256) void normalize_bf16(
    const float* __restrict__ t1, const float* __restrict__ t2,
    unsigned short* __restrict__ o1, unsigned short* __restrict__ o2)
{
    int b = blockIdx.x;
    int t = threadIdx.x;
    const float* src;
    unsigned short* dst;
    if (b < NROW) { src = t1 + (size_t)b * KDIM;          dst = o1 + (size_t)b * KDIM; }
    else          { src = t2 + (size_t)(b - NROW) * KDIM; dst = o2 + (size_t)(b - NROW) * KDIM; }

    float4 v = reinterpret_cast<const float4*>(src)[t];
    float ss = v.x * v.x + v.y * v.y + v.z * v.z + v.w * v.w;
    #pragma unroll
    for (int d = 32; d >= 1; d >>= 1) ss += __shfl_xor(ss, d, 64);

    __shared__ float wsum[4];
    int wave = t >> 6;
    if ((t & 63) == 0) wsum[wave] = ss;
    __syncthreads();
    float inv = 1.0f / (sqrtf(wsum[0] + wsum[1] + wsum[2] + wsum[3]) + 1e-8f);

    ushort4 o;
    o.x = f2bf(v.x * inv);
    o.y = f2bf(v.y * inv);
    o.z = f2bf(v.z * inv);
    o.w = f2bf(v.w * inv);
    reinterpret_cast<ushort4*>(dst)[t] = o;
}

// ---------------------------------------------------------------------------
// Kernel 2: skewed cost: skew[i + ((j>>2)&63)][j] = 1 - dot(t1n[i], t2n[j])
// ---------------------------------------------------------------------------
__global__ __launch_bounds__(256) void gemm_cost(
    const unsigned short* __restrict__ A,
    const unsigned short* __restrict__ B,
    unsigned short* __restrict__ Cs)    // skewed [SKROWS][4096]
{
    __shared__ __align__(16) unsigned short As[BM * BK];
    __shared__ __align__(16) unsigned short Bs[BM * BK];

    int t    = threadIdx.x;
    int lane = t & 63;
    int wave = t >> 6;
    int i0   = blockIdx.y * BM;
    int j0   = blockIdx.x * BM;

    f32x4 acc[4][4];
    f32x4 zero = {0.f, 0.f, 0.f, 0.f};
    #pragma unroll
    for (int m = 0; m < 4; ++m)
        #pragma unroll
        for (int n = 0; n < 4; ++n) acc[m][n] = zero;

    int frow = lane & 15;
    int fk   = (lane >> 4) * 8;
    int wr   = (wave >> 1) * 64;
    int wc   = (wave & 1) * 64;

    int srow = t >> 2;
    int scb  = (t & 3) * 8;

    uint4 ra0, ra1, rb0, rb1;
    {
        ra0 = *reinterpret_cast<const uint4*>(A + (size_t)(i0 + srow) * KDIM + scb);
        ra1 = *reinterpret_cast<const uint4*>(A + (size_t)(i0 + 64 + srow) * KDIM + scb);
        rb0 = *reinterpret_cast<const uint4*>(B + (size_t)(j0 + srow) * KDIM + scb);
        rb1 = *reinterpret_cast<const uint4*>(B + (size_t)(j0 + 64 + srow) * KDIM + scb);
    }

    for (int k0 = 0; k0 < KDIM; k0 += BK) {
        __syncthreads();
        *reinterpret_cast<uint4*>(As + (size_t)t * 8)         = ra0;
        *reinterpret_cast<uint4*>(As + (size_t)(256 + t) * 8) = ra1;
        *reinterpret_cast<uint4*>(Bs + (size_t)t * 8)         = rb0;
        *reinterpret_cast<uint4*>(Bs + (size_t)(256 + t) * 8) = rb1;
        __syncthreads();

        if (k0 + BK < KDIM) {
            int kn = k0 + BK;
            ra0 = *reinterpret_cast<const uint4*>(A + (size_t)(i0 + srow) * KDIM + kn + scb);
            ra1 = *reinterpret_cast<const uint4*>(A + (size_t)(i0 + 64 + srow) * KDIM + kn + scb);
            rb0 = *reinterpret_cast<const uint4*>(B + (size_t)(j0 + srow) * KDIM + kn + scb);
            rb1 = *reinterpret_cast<const uint4*>(B + (size_t)(j0 + 64 + srow) * KDIM + kn + scb);
        }

        bf16x8 af[4], bfr[4];
        #pragma unroll
        for (int m = 0; m < 4; ++m)
            af[m] = *reinterpret_cast<const bf16x8*>(As + (wr + m * 16 + frow) * BK + fk);
        #pragma unroll
        for (int n = 0; n < 4; ++n)
            bfr[n] = *reinterpret_cast<const bf16x8*>(Bs + (wc + n * 16 + frow) * BK + fk);

        #pragma unroll
        for (int m = 0; m < 4; ++m)
            #pragma unroll
            for (int n = 0; n < 4; ++n)
                acc[m][n] = __builtin_amdgcn_mfma_f32_16x16x32_bf16(af[m], bfr[n], acc[m][n], 0, 0, 0);
    }

    int crow = (lane >> 4) * 4;
    int ccol = lane & 15;
    #pragma unroll
    for (int n = 0; n < 4; ++n) {
        const int j  = j0 + wc + n * 16 + ccol;
        const int Lj = (j >> 2) & 63;
        #pragma unroll
        for (int m = 0; m < 4; ++m) {
            const int ibase = i0 + wr + m * 16 + crow;
            #pragma unroll
            for (int q = 0; q < 4; ++q)
                Cs[(size_t)(ibase + q + Lj) * NCOL + j] = f2bf(1.0f - acc[m][n][q]);
        }
    }
}

// ---------------------------------------------------------------------------
// Kernel 3: systolic DTW, 4 WGs x 4 waves, 32-row blocks (epoch halving).
// Wave v of WG w processes block ib = e - 3v - DLAG*w at epoch e.
// Intra-WG: outRow LDS ring (128 rows); wave lag 3 (producer 2 blocks ahead
// + strict epoch separation). Inter-WG: 3 global ring interfaces, 32 slots
// per block via lanes 0..31, asm sc0/sc1 preload 1 block ahead, counted
// vmcnt binds rv0 (rule #18). Cost: 2-slot x 16KB LDS double-buffer/wave,
// 16x gll16 prefetch 1 ahead. Uniform VMEM issue per epoch (gPro dummy garb
// atomic on idle epochs) -> exact waits vmcnt(17/17/16).
// ---------------------------------------------------------------------------
__global__ __launch_bounds__(256, 1) void dtw_systolic(
    const unsigned short* __restrict__ cost,   // skewed [SKROWS][4096]
    unsigned long long* __restrict__ ring,     // [3][4096] + garb[4][64]
    float* __restrict__ out)
{
    __shared__ __align__(16) unsigned char clds[4 * 2 * 16384]; // [wave][slot][16KB]
    __shared__ float outRow[4][128];    // row-indexed boundary ring per stripe
    __shared__ float outRowD[4][64];    // per-lane dump (conflict-free)

    const int w    = blockIdx.x;
    const int tid  = threadIdx.x;
    const int v    = tid >> 6;
    const int lane = tid & 63;
    const int stripe = 4 * w + v;
    const bool gCon  = (v == 0 && w > 0);
    const bool gPro  = (v == 3 && w < 3);
    const bool first = (stripe == 0);
    const char* skewb = (const char*)cost;
    const unsigned long long* rseg = ring + (size_t)(w > 0 ? w - 1 : 0) * 4096;
    unsigned long long* wseg = ring + (size_t)w * 4096;
    unsigned long long* garb = ring + (size_t)3 * 4096 + w * 64;
    const unsigned l32 = (unsigned)(lane & 31);
    const unsigned stripeByte = (unsigned)stripe * 512u + ((unsigned)(lane & 31) << 4);
    unsigned char* myclds = clds + v * 32768;

    float pd0 = INFV, pd1 = INFV, pd2 = INFV, pd3 = INFV;
    float lprev = (first && lane == 0) ? 0.0f : INFV;   // DP origin seed
    float d3p = INFV;
    unsigned ansb = INFBITS;
    unsigned long long rv0 = 0;

#define GLL16S(STG) { int sg_ = (STG); sg_ = sg_ < 0 ? 0 : (sg_ > NBLK32 - 1 ? NBLK32 - 1 : sg_); \
    unsigned char* ldsb_ = myclds + (sg_ & 1) * 16384; \
    _Pragma("unroll") \
    for (int g_ = 0; g_ < 16; ++g_) { \
        int sr_ = 32 * sg_ + 2 * g_ + (lane >> 5); \
        if (sr_ > SKROWS - 1) sr_ = SKROWS - 1; \
        gll16(skewb + (size_t)sr_ * 8192 + stripeByte, ldsb_ + g_ * 1024); } }

// ring preload via asm (invisible to compiler waitcnt pass); 32 slots/block
#define RINGLD(DST, BI) { int pb_ = (BI); pb_ = pb_ < 0 ? 0 : (pb_ > 127 ? 127 : pb_); \
    const unsigned off_ = (32u * (unsigned)pb_ + l32) * 8u; \
    asm volatile("global_load_dwordx2 %0, %1, %2 sc0 sc1" \
                 : "=v"(DST) : "v"(off_), "s"(rseg) : "memory"); }

// pure-VALU step; conflict-free store (lane63 -> outRow, others -> own dump)
#define DCOMP(K, CU) { \
    const unsigned rbK = (unsigned)__builtin_amdgcn_readlane(rvhi, (K)); \
    const float lcur = __uint_as_float((unsigned)__builtin_amdgcn_update_dpp( \
        (int)rbK, (int)__float_as_uint(d3p), 0x138, 0xf, 0xf, false)); \
    const float c0 = __uint_as_float(CU.x << 16); \
    const float c1 = __uint_as_float(CU.x & 0xffff0000u); \
    const float c2 = __uint_as_float(CU.y << 16); \
    const float c3 = __uint_as_float(CU.y & 0xffff0000u); \
    const float n0 = c0 + fminf(pd0, lprev); \
    const float n1 = c1 + fminf(pd1, pd0); \
    const float n2 = c2 + fminf(pd2, pd1); \
    const float n3 = c3 + fminf(pd3, pd2); \
    const float e0 = fminf(lcur + c0, n0); \
    const float e1 = fminf(e0 + c1, n1); \
    const float e2 = fminf(e1 + c2, n2); \
    const float e3 = fminf(e2 + c3, n3); \
    float* sp_ = (lane == 63) ? &outRow[v][(unsigned)(rowbase + (K)) & 127u] \
                              : &outRowD[v][lane]; \
    *sp_ = e3; \
    ansb = (tjb + (K) == 4158) ? __float_as_uint(e3) : ansb; \
    lprev = lcur; d3p = e3; \
    pd0 = e0; pd1 = e1; pd2 = e2; pd3 = e3; }

    // prologue: wave 0 stages block 0 (+ring slot 0 for gCon)
    if (v == 0) {
        GLL16S(0)
        if (gCon) RINGLD(rv0, 0)
    }

    #pragma unroll 1
    for (int e = 0; e < EMAX; ++e) {
        CFENCE;
        asm volatile("s_waitcnt lgkmcnt(0)" ::: "memory");  // LDS writes visible
        __builtin_amdgcn_s_barrier();
        CFENCE;

        const int ib = e - 3 * v - DLAG * w;   // this wave's block this epoch

        GLL16S(ib + 1)                     // prefetch next block -> other slot
        unsigned long long rvN = 0;
        if (gCon) RINGLD(rvN, ib + 1)

        if (gCon) {
            // 17 ops/epoch (16 gll + 1 ringld); prev epoch's 17 are oldest.
            asm volatile("s_waitcnt vmcnt(17)" : "+v"(rv0) :: "memory");
        } else if (gPro) {
            // 17 ops/epoch (16 gll + 1 atomic at end, dummy on idle epochs)
            asm volatile("s_waitcnt vmcnt(17)" ::: "memory");
        } else {
            asm volatile("s_waitcnt vmcnt(16)" ::: "memory");
        }

        if (ib >= 0 && ib < NBLK32) {
            // batch-load the 32 cost uint2s into named regs
            const uint2* lu = reinterpret_cast<const uint2*>(
                myclds + (ib & 1) * 16384 + (lane << 3));
            const uint2 cc0  = lu[0 * 64],  cc1  = lu[1 * 64];
            const uint2 cc2  = lu[2 * 64],  cc3  = lu[3 * 64];
            const uint2 cc4  = lu[4 * 64],  cc5  = lu[5 * 64];
            const uint2 cc6  = lu[6 * 64],  cc7  = lu[7 * 64];
            const uint2 cc8  = lu[8 * 64],  cc9  = lu[9 * 64];
            const uint2 cc10 = lu[10 * 64], cc11 = lu[11 * 64];
            const uint2 cc12 = lu[12 * 64], cc13 = lu[13 * 64];
            const uint2 cc14 = lu[14 * 64], cc15 = lu[15 * 64];
            const uint2 cc16 = lu[16 * 64], cc17 = lu[17 * 64];
            const uint2 cc18 = lu[18 * 64], cc19 = lu[19 * 64];
            const uint2 cc20 = lu[20 * 64], cc21 = lu[21 * 64];
            const uint2 cc22 = lu[22 * 64], cc23 = lu[23 * 64];
            const uint2 cc24 = lu[24 * 64], cc25 = lu[25 * 64];
            const uint2 cc26 = lu[26 * 64], cc27 = lu[27 * 64];
            const uint2 cc28 = lu[28 * 64], cc29 = lu[29 * 64];
            const uint2 cc30 = lu[30 * 64], cc31 = lu[31 * 64];

            // resolve boundary input (lanes 0..31 hold rows 32ib..32ib+31)
            int rvhi;
            if (gCon) {
                if (ib < 128) {
                    const unsigned expt = 32u * (unsigned)ib + l32 + 1u;
                    while (__ballot((unsigned)rv0 == expt) != ~0ull)
                        rv0 = __hip_atomic_load(rseg + 32u * (unsigned)ib + l32,
                                                __ATOMIC_RELAXED, __HIP_MEMORY_SCOPE_AGENT);
                }
                rvhi = (int)(unsigned)(rv0 >> 32);
            } else if (v > 0) {
                rvhi = (int)__float_as_uint(
                    outRow[v - 1][(32u * (unsigned)ib + l32) & 127u]);
            } else {
                rvhi = (int)INFBITS;        // stripe 0: left edge = +INF
            }

            const int rowbase = 32 * ib - 63;
            const int tjb = 32 * ib;

            DCOMP(0,  cc0)  DCOMP(1,  cc1)  DCOMP(2,  cc2)  DCOMP(3,  cc3)
            DCOMP(4,  cc4)  DCOMP(5,  cc5)  DCOMP(6,  cc6)  DCOMP(7,  cc7)
            DCOMP(8,  cc8)  DCOMP(9,  cc9)  DCOMP(10, cc10) DCOMP(11, cc11)
            DCOMP(12, cc12) DCOMP(13, cc13) DCOMP(14, cc14) DCOMP(15, cc15)
            DCOMP(16, cc16) DCOMP(17, cc17) DCOMP(18, cc18) DCOMP(19, cc19)
            DCOMP(20, cc20) DCOMP(21, cc21) DCOMP(22, cc22) DCOMP(23, cc23)
            DCOMP(24, cc24) DCOMP(25, cc25) DCOMP(26, cc26) DCOMP(27, cc27)
            DCOMP(28, cc28) DCOMP(29, cc29) DCOMP(30, cc30) DCOMP(31, cc31)
        }

        if (gPro) {     // publish 32 boundary rows (or garb; ALWAYS 1 atomic)
            const int r = 32 * ib - 63 + (int)l32;
            const float bv = outRow[3][(unsigned)r & 127u];
            const bool valid = (lane < 32) && (ib >= 0) && (ib < NBLK32) &&
                               (r >= 0) && (r <= 4095);
            if (lane < 32) {
                const unsigned long long pk =
                    ((unsigned long long)__float_as_uint(bv) << 32) | (unsigned)(r + 1);
                unsigned long long* sp = valid ? (wseg + r) : (garb + lane);
                (void)__hip_atomic_exchange(sp, pk, __ATOMIC_RELAXED,
                                            __HIP_MEMORY_SCOPE_AGENT);
            }
        }

        rv0 = rvN;
    }

#undef GLL16S
#undef RINGLD
#undef DCOMP

    if (stripe == 15 && lane == 63) out[0] = 1.0f / (1.0f + __uint_as_float(ansb));
}

// ---------------------------------------------------------------------------
extern "C" void kernel_launch(void* const* d_in, const int* in_sizes, int n_in,
                              void* d_out, int out_size, void* d_ws, size_t ws_size,
                              hipStream_t stream)
{
    const float* t1 = (const float*)d_in[0];
    const float* t2 = (const float*)d_in[1];
    float* out = (float*)d_out;

    char* ws = (char*)d_ws;
    unsigned short* t1n  = (unsigned short*)ws;                                   // 8 MB
    unsigned short* t2n  = (unsigned short*)(ws + (size_t)NROW * KDIM * 2);       // 8 MB
    unsigned short* skew = (unsigned short*)(ws + (size_t)16 * 1024 * 1024);      // 34.1 MB
    unsigned long long* ring = (unsigned long long*)(ws + (size_t)52 * 1024 * 1024);
    // ring: 3 interface segments x 4096 slots + 4x64 garb slots (~130 KB)

    hipMemsetAsync(ring, 0, (size_t)(3 * 4096 + 4 * 64) * 8, stream);
    normalize_bf16<<<2 * NROW, 256, 0, stream>>>(t1, t2, t1n, t2n);
    gemm_cost<<<dim3(NCOL / BM, NROW / BM), 256, 0, stream>>>(t1n, t2n, skew);
    dtw_systolic<<<4, 256, 0, stream>>>(skew, ring, out);
}

// Round 15
// 516.983 us; speedup vs baseline: 1.5419x; 1.1621x over previous
//
#include <hip/hip_runtime.h>
#include <hip/hip_bf16.h>
#include <stdint.h>

#define KDIM 1024
#define NROW 4096
#define NCOL 4096
#define INFV 1e30f
#define INFBITS 0x7149F2CAu     // bits of 1e30f
#define BM 128
#define BK 32

#define SKROWS 4160             // skewed cost rows
#define NBLK32 130              // 32-step blocks (tj 0..4159)
#define NWG    16

typedef __bf16 bf16x8 __attribute__((ext_vector_type(8)));
typedef float f32x4 __attribute__((ext_vector_type(4)));

#define CFENCE asm volatile("" ::: "memory")

__device__ __forceinline__ unsigned short f2bf(float f) {
    __hip_bfloat16 h = __float2bfloat16(f);
    return *reinterpret_cast<unsigned short*>(&h);
}

__device__ __forceinline__ void gll16(const void* gsrc, void* ldst) {
    __builtin_amdgcn_global_load_lds(
        (const __attribute__((address_space(1))) void*)gsrc,
        (__attribute__((address_space(3))) void*)ldst, 16, 0, 0);
}

// ---------------------------------------------------------------------------
// Kernel 1: row-normalize both trajectories, emit bf16
// ---------------------------------------------------------------------------
__global__ __launch_bounds__(256) void normalize_bf16(
    const float* __restrict__ t1, const float* __restrict__ t2,
    unsigned short* __restrict__ o1, unsigned short* __restrict__ o2)
{
    int b = blockIdx.x;
    int t = threadIdx.x;
    const float* src;
    unsigned short* dst;
    if (b < NROW) { src = t1 + (size_t)b * KDIM;          dst = o1 + (size_t)b * KDIM; }
    else          { src = t2 + (size_t)(b - NROW) * KDIM; dst = o2 + (size_t)(b - NROW) * KDIM; }

    float4 v = reinterpret_cast<const float4*>(src)[t];
    float ss = v.x * v.x + v.y * v.y + v.z * v.z + v.w * v.w;
    #pragma unroll
    for (int d = 32; d >= 1; d >>= 1) ss += __shfl_xor(ss, d, 64);

    __shared__ float wsum[4];
    int wave = t >> 6;
    if ((t & 63) == 0) wsum[wave] = ss;
    __syncthreads();
    float inv = 1.0f / (sqrtf(wsum[0] + wsum[1] + wsum[2] + wsum[3]) + 1e-8f);

    ushort4 o;
    o.x = f2bf(v.x * inv);
    o.y = f2bf(v.y * inv);
    o.z = f2bf(v.z * inv);
    o.w = f2bf(v.w * inv);
    reinterpret_cast<ushort4*>(dst)[t] = o;
}

// ---------------------------------------------------------------------------
// Kernel 2: skewed cost: skew[i + ((j>>2)&63)][j] = 1 - dot(t1n[i], t2n[j])
// ---------------------------------------------------------------------------
__global__ __launch_bounds__(256) void gemm_cost(
    const unsigned short* __restrict__ A,
    const unsigned short* __restrict__ B,
    unsigned short* __restrict__ Cs)    // skewed [SKROWS][4096]
{
    __shared__ __align__(16) unsigned short As[BM * BK];
    __shared__ __align__(16) unsigned short Bs[BM * BK];

    int t    = threadIdx.x;
    int lane = t & 63;
    int wave = t >> 6;
    int i0   = blockIdx.y * BM;
    int j0   = blockIdx.x * BM;

    f32x4 acc[4][4];
    f32x4 zero = {0.f, 0.f, 0.f, 0.f};
    #pragma unroll
    for (int m = 0; m < 4; ++m)
        #pragma unroll
        for (int n = 0; n < 4; ++n) acc[m][n] = zero;

    int frow = lane & 15;
    int fk   = (lane >> 4) * 8;
    int wr   = (wave >> 1) * 64;
    int wc   = (wave & 1) * 64;

    int srow = t >> 2;
    int scb  = (t & 3) * 8;

    uint4 ra0, ra1, rb0, rb1;
    {
        ra0 = *reinterpret_cast<const uint4*>(A + (size_t)(i0 + srow) * KDIM + scb);
        ra1 = *reinterpret_cast<const uint4*>(A + (size_t)(i0 + 64 + srow) * KDIM + scb);
        rb0 = *reinterpret_cast<const uint4*>(B + (size_t)(j0 + srow) * KDIM + scb);
        rb1 = *reinterpret_cast<const uint4*>(B + (size_t)(j0 + 64 + srow) * KDIM + scb);
    }

    for (int k0 = 0; k0 < KDIM; k0 += BK) {
        __syncthreads();
        *reinterpret_cast<uint4*>(As + (size_t)t * 8)         = ra0;
        *reinterpret_cast<uint4*>(As + (size_t)(256 + t) * 8) = ra1;
        *reinterpret_cast<uint4*>(Bs + (size_t)t * 8)         = rb0;
        *reinterpret_cast<uint4*>(Bs + (size_t)(256 + t) * 8) = rb1;
        __syncthreads();

        if (k0 + BK < KDIM) {
            int kn = k0 + BK;
            ra0 = *reinterpret_cast<const uint4*>(A + (size_t)(i0 + srow) * KDIM + kn + scb);
            ra1 = *reinterpret_cast<const uint4*>(A + (size_t)(i0 + 64 + srow) * KDIM + kn + scb);
            rb0 = *reinterpret_cast<const uint4*>(B + (size_t)(j0 + srow) * KDIM + kn + scb);
            rb1 = *reinterpret_cast<const uint4*>(B + (size_t)(j0 + 64 + srow) * KDIM + kn + scb);
        }

        bf16x8 af[4], bfr[4];
        #pragma unroll
        for (int m = 0; m < 4; ++m)
            af[m] = *reinterpret_cast<const bf16x8*>(As + (wr + m * 16 + frow) * BK + fk);
        #pragma unroll
        for (int n = 0; n < 4; ++n)
            bfr[n] = *reinterpret_cast<const bf16x8*>(Bs + (wc + n * 16 + frow) * BK + fk);

        #pragma unroll
        for (int m = 0; m < 4; ++m)
            #pragma unroll
            for (int n = 0; n < 4; ++n)
                acc[m][n] = __builtin_amdgcn_mfma_f32_16x16x32_bf16(af[m], bfr[n], acc[m][n], 0, 0, 0);
    }

    int crow = (lane >> 4) * 4;
    int ccol = lane & 15;
    #pragma unroll
    for (int n = 0; n < 4; ++n) {
        const int j  = j0 + wc + n * 16 + ccol;
        const int Lj = (j >> 2) & 63;
        #pragma unroll
        for (int m = 0; m < 4; ++m) {
            const int ibase = i0 + wr + m * 16 + crow;
            #pragma unroll
            for (int q = 0; q < 4; ++q)
                Cs[(size_t)(ibase + q + Lj) * NCOL + j] = f2bf(1.0f - acc[m][n][q]);
        }
    }
}

// ---------------------------------------------------------------------------
// ring_init: prefill dummy segment (index 15), read by WG 0: tag = row+1
// (always valid), value = +INF -> WG0 runs the same code, never polls.
// ---------------------------------------------------------------------------
__global__ __launch_bounds__(256) void ring_init(unsigned long long* __restrict__ ring)
{
    int i = blockIdx.x * 256 + threadIdx.x;
    ring[(size_t)15 * NROW + i] =
        ((unsigned long long)INFBITS << 32) | (unsigned)(i + 1);
}

// ---------------------------------------------------------------------------
// Kernel 3: systolic DTW, 16 WGs x 1 wave, FREE-RUNNING (no barriers).
// Stripe w owns cols [256w, +256); lane L: 4 cols; 32-row blocks ib=0..129.
// Pacing is purely by ring tags: 3-block asm tag preload + producer leading
// by 2 blocks => steady-state throughput = per-block compute; the ~2.4us
// cross-XCD visibility only appears in the 15-hop pipeline fill (R13's
// barrier lockstep had no consumption->production buffering, so visibility
// taxed every block). One wave per CU: exclusive LDS pipe, no lgkmcnt(0)
// drains, no s_barrier. VMEM per block: 16 gll + 1 asm ringld + 1 publish
// atomic = 18, one counted vmcnt(19) binding rv0 (rule #18).
// Lane63's 32 row-values batch via private LDS -> one 32-lane publish.
// ---------------------------------------------------------------------------
__global__ __launch_bounds__(64, 1) void dtw_systolic(
    const unsigned short* __restrict__ cost,   // skewed [SKROWS][4096]
    unsigned long long* __restrict__ ring,     // [16][4096] + garb[16][64]
    float* __restrict__ out)
{
    __shared__ __align__(16) unsigned char clds[2 * 16384];  // cost double-buffer
    __shared__ float outT[32];     // lane63's row-values for this block
    __shared__ float outD[64];     // per-lane dump (conflict-free)

    const int w    = blockIdx.x;
    const int lane = threadIdx.x;
    const char* skewb = (const char*)cost;
    const unsigned long long* rseg = ring + (size_t)((w == 0) ? 15 : (w - 1)) * NROW;
    unsigned long long* wseg = (w < NWG - 1) ? (ring + (size_t)w * NROW)
                                             : (ring + (size_t)NWG * NROW + w * 64);
    unsigned long long* garb = ring + (size_t)NWG * NROW + w * 64;
    const unsigned l32 = (unsigned)(lane & 31);
    const unsigned stripeByte = (unsigned)w * 512u + ((unsigned)(lane & 31) << 4);

    float pd0 = INFV, pd1 = INFV, pd2 = INFV, pd3 = INFV;
    float lprev = (w == 0 && lane == 0) ? 0.0f : INFV;   // DP origin seed
    float d3p = INFV;
    unsigned ansb = INFBITS;
    unsigned long long rv0 = 0, rv1 = 0, rv2 = 0;

#define GLL16S(STG) { int sg_ = (STG); sg_ = sg_ < 0 ? 0 : (sg_ > NBLK32 - 1 ? NBLK32 - 1 : sg_); \
    unsigned char* ldsb_ = clds + (sg_ & 1) * 16384; \
    _Pragma("unroll") \
    for (int g_ = 0; g_ < 16; ++g_) { \
        int sr_ = 32 * sg_ + 2 * g_ + (lane >> 5); \
        if (sr_ > SKROWS - 1) sr_ = SKROWS - 1; \
        gll16(skewb + (size_t)sr_ * 8192 + stripeByte, ldsb_ + g_ * 1024); } }

// asm tag/value preload: invisible to compiler waitcnt pass, L2-bypass
#define RINGLD(DST, BI) { int pb_ = (BI); pb_ = pb_ < 0 ? 0 : (pb_ > 127 ? 127 : pb_); \
    const unsigned off_ = (32u * (unsigned)pb_ + l32) * 8u; \
    asm volatile("global_load_dwordx2 %0, %1, %2 sc0 sc1" \
                 : "=v"(DST) : "v"(off_), "s"(rseg) : "memory"); }

// pure-VALU step; lane63 records e3 in outT[K], others dump to own slot
#define DCOMP(K, CU) { \
    const unsigned rbK = (unsigned)__builtin_amdgcn_readlane(rvhi, (K)); \
    const float lcur = __uint_as_float((unsigned)__builtin_amdgcn_update_dpp( \
        (int)rbK, (int)__float_as_uint(d3p), 0x138, 0xf, 0xf, false)); \
    const float c0 = __uint_as_float(CU.x << 16); \
    const float c1 = __uint_as_float(CU.x & 0xffff0000u); \
    const float c2 = __uint_as_float(CU.y << 16); \
    const float c3 = __uint_as_float(CU.y & 0xffff0000u); \
    const float n0 = c0 + fminf(pd0, lprev); \
    const float n1 = c1 + fminf(pd1, pd0); \
    const float n2 = c2 + fminf(pd2, pd1); \
    const float n3 = c3 + fminf(pd3, pd2); \
    const float e0 = fminf(lcur + c0, n0); \
    const float e1 = fminf(e0 + c1, n1); \
    const float e2 = fminf(e1 + c2, n2); \
    const float e3 = fminf(e2 + c3, n3); \
    float* sp_ = (lane == 63) ? &outT[K] : &outD[lane]; \
    *sp_ = e3; \
    ansb = (tjb + (K) == 4158) ? __float_as_uint(e3) : ansb; \
    lprev = lcur; d3p = e3; \
    pd0 = e0; pd1 = e1; pd2 = e2; pd3 = e3; }

    // prologue: stage block 0, preload tags for blocks 0..2
    GLL16S(0)
    RINGLD(rv0, 0) RINGLD(rv1, 1) RINGLD(rv2, 2)
    CFENCE;

    #pragma unroll 1
    for (int ib = 0; ib < NBLK32; ++ib) {
        GLL16S(ib + 1)                     // next block -> other slot
        unsigned long long rvN;
        RINGLD(rvN, ib + 3)
        CFENCE;
        // wait: prev block's 16 glls (and transitively rv0's load) done
        asm volatile("s_waitcnt vmcnt(19)" : "+v"(rv0) :: "memory");

        // tag check for this block (rows 32ib..32ib+31); dummy seg for w=0
        if (ib < 128) {
            const unsigned expt = 32u * (unsigned)ib + l32 + 1u;
            while (__ballot((unsigned)rv0 == expt) != ~0ull)
                rv0 = __hip_atomic_load(rseg + 32u * (unsigned)ib + l32,
                                        __ATOMIC_RELAXED, __HIP_MEMORY_SCOPE_AGENT);
        }
        const int rvhi = (int)(unsigned)(rv0 >> 32);

        // batch-load the 32 cost uint2s into named regs
        const uint2* lu = reinterpret_cast<const uint2*>(
            clds + (ib & 1) * 16384 + (lane << 3));
        const uint2 cc0  = lu[0 * 64],  cc1  = lu[1 * 64];
        const uint2 cc2  = lu[2 * 64],  cc3  = lu[3 * 64];
        const uint2 cc4  = lu[4 * 64],  cc5  = lu[5 * 64];
        const uint2 cc6  = lu[6 * 64],  cc7  = lu[7 * 64];
        const uint2 cc8  = lu[8 * 64],  cc9  = lu[9 * 64];
        const uint2 cc10 = lu[10 * 64], cc11 = lu[11 * 64];
        const uint2 cc12 = lu[12 * 64], cc13 = lu[13 * 64];
        const uint2 cc14 = lu[14 * 64], cc15 = lu[15 * 64];
        const uint2 cc16 = lu[16 * 64], cc17 = lu[17 * 64];
        const uint2 cc18 = lu[18 * 64], cc19 = lu[19 * 64];
        const uint2 cc20 = lu[20 * 64], cc21 = lu[21 * 64];
        const uint2 cc22 = lu[22 * 64], cc23 = lu[23 * 64];
        const uint2 cc24 = lu[24 * 64], cc25 = lu[25 * 64];
        const uint2 cc26 = lu[26 * 64], cc27 = lu[27 * 64];
        const uint2 cc28 = lu[28 * 64], cc29 = lu[29 * 64];
        const uint2 cc30 = lu[30 * 64], cc31 = lu[31 * 64];

        const int rowbase = 32 * ib - 63;
        const int tjb = 32 * ib;

        DCOMP(0,  cc0)  DCOMP(1,  cc1)  DCOMP(2,  cc2)  DCOMP(3,  cc3)
        DCOMP(4,  cc4)  DCOMP(5,  cc5)  DCOMP(6,  cc6)  DCOMP(7,  cc7)
        DCOMP(8,  cc8)  DCOMP(9,  cc9)  DCOMP(10, cc10) DCOMP(11, cc11)
        DCOMP(12, cc12) DCOMP(13, cc13) DCOMP(14, cc14) DCOMP(15, cc15)
        DCOMP(16, cc16) DCOMP(17, cc17) DCOMP(18, cc18) DCOMP(19, cc19)
        DCOMP(20, cc20) DCOMP(21, cc21) DCOMP(22, cc22) DCOMP(23, cc23)
        DCOMP(24, cc24) DCOMP(25, cc25) DCOMP(26, cc26) DCOMP(27, cc27)
        DCOMP(28, cc28) DCOMP(29, cc29) DCOMP(30, cc30) DCOMP(31, cc31)

        // publish 32 boundary rows (lane k -> row rowbase+k), garb if invalid
        {
            const float bv = outT[l32];
            const int r = rowbase + (int)l32;
            const bool valid = (lane < 32) && (r >= 0) && (r <= 4095) &&
                               (w < NWG - 1);
            if (lane < 32) {
                const unsigned long long pk =
                    ((unsigned long long)__float_as_uint(bv) << 32) | (unsigned)(r + 1);
                unsigned long long* sp = valid ? (wseg + r) : (garb + lane);
                (void)__hip_atomic_exchange(sp, pk, __ATOMIC_RELAXED,
                                            __HIP_MEMORY_SCOPE_AGENT);
            }
        }
        CFENCE;

        rv0 = rv1; rv1 = rv2; rv2 = rvN;
    }

#undef GLL16S
#undef RINGLD
#undef DCOMP

    if (w == NWG - 1 && lane == 63) out[0] = 1.0f / (1.0f + __uint_as_float(ansb));
}

// ---------------------------------------------------------------------------
extern "C" void kernel_launch(void* const* d_in, const int* in_sizes, int n_in,
                              void* d_out, int out_size, void* d_ws, size_t ws_size,
                              hipStream_t stream)
{
    const float* t1 = (const float*)d_in[0];
    const float* t2 = (const float*)d_in[1];
    float* out = (float*)d_out;

    char* ws = (char*)d_ws;
    unsigned short* t1n  = (unsigned short*)ws;                                   // 8 MB
    unsigned short* t2n  = (unsigned short*)(ws + (size_t)NROW * KDIM * 2);       // 8 MB
    unsigned short* skew = (unsigned short*)(ws + (size_t)16 * 1024 * 1024);      // 34.1 MB
    unsigned long long* ring = (unsigned long long*)(ws + (size_t)52 * 1024 * 1024);
    // ring: segs 0..14 real interfaces, seg 15 = dummy-INF for WG0,
    // then 16x64 garb slots (~520 KB total)

    hipMemsetAsync(ring, 0, (size_t)15 * NROW * 8, stream);
    ring_init<<<NROW / 256, 256, 0, stream>>>(ring);
    normalize_bf16<<<2 * NROW, 256, 0, stream>>>(t1, t2, t1n, t2n);
    gemm_cost<<<dim3(NCOL / BM, NROW / BM), 256, 0, stream>>>(t1n, t2n, skew);
    dtw_systolic<<<NWG, 64, 0, stream>>>(skew, ring, out);
}